// Round 1
// 210.833 us; speedup vs baseline: 1.0543x; 1.0543x over previous
//
#include <hip/hip_runtime.h>
#include <math.h>

#define T_SEQ 2048
#define NH 16
#define HD 64
#define CEMB 1024
#define NEGINF -3.0e38f
#define LOG2E 1.4426950408889634f

typedef unsigned short ushort;
typedef unsigned int uint;
typedef __attribute__((ext_vector_type(8))) short short8;
typedef __attribute__((ext_vector_type(4))) float f32x4;

#if __has_builtin(__builtin_amdgcn_exp2f)
#define EXP2(x) __builtin_amdgcn_exp2f(x)
#else
#define EXP2(x) exp2f(x)
#endif

__device__ __forceinline__ float b2f(ushort h) {
    union { uint u; float f; } cv; cv.u = ((uint)h) << 16; return cv.f;
}
__device__ __forceinline__ ushort f2b(float f) {
    union { float f; uint u; } cv; cv.f = f;
    return (ushort)((cv.u + 0x7FFF + ((cv.u >> 16) & 1)) >> 16);
}
__device__ __forceinline__ ushort f2b_fast(float f) {   // round-half-up, 2 ops
    union { float f; uint u; } cv; cv.f = f;
    return (ushort)((cv.u + 0x8000) >> 16);
}
// pack two f32 -> packed bf16 pair (round-half-up) with one v_perm_b32
__device__ __forceinline__ uint pack_bf16(float a, float b) {
    union { float f; uint u; } ua, ub; ua.f = a; ub.f = b;
    return __builtin_amdgcn_perm(ub.u + 0x8000u, ua.u + 0x8000u, 0x07060302u);
}
__device__ __forceinline__ void gl2lds16(const ushort* g, ushort* l) {
    __builtin_amdgcn_global_load_lds(
        (const __attribute__((address_space(1))) void*)g,
        (__attribute__((address_space(3))) void*)l, 16, 0, 0);
}

// ---------------------------------------------------------------------------
// merged f32 -> bf16 convert for x / Wqkv / Wproj (one launch)
// ---------------------------------------------------------------------------
__global__ __launch_bounds__(256) void convert_all_kernel(
    const float* __restrict__ x, const float* __restrict__ wqkv,
    const float* __restrict__ wproj,
    ushort* __restrict__ xb, ushort* __restrict__ wqkvb,
    ushort* __restrict__ wprojb)
{
    const int bid = blockIdx.x;
    const float* src; ushort* dst; int off;
    if (bid < 4096)      { src = x;     dst = xb;     off = bid; }
    else if (bid < 7168) { src = wqkv;  dst = wqkvb;  off = bid - 4096; }
    else                 { src = wproj; dst = wprojb; off = bid - 7168; }
    const int i = (off * 256 + threadIdx.x) * 4;
    const float4 v = *(const float4*)&src[i];
    ushort4 o;
    o.x = f2b(v.x); o.y = f2b(v.y); o.z = f2b(v.z); o.w = f2b(v.w);
    *(ushort4*)&dst[i] = o;
}

// ---------------------------------------------------------------------------
// Wlow: rows 3072..3327 of the extended B matrix (appended to wqkvb).
// Blocks 32..47: precompute bias_pre[h][t] = w_disc[h]*log2e*d_bias[h][t].
// ---------------------------------------------------------------------------
__global__ __launch_bounds__(256) void wlow_kernel(
    const float* __restrict__ Wqkv, const float* __restrict__ W_recip,
    const float* __restrict__ w_disc, const float* __restrict__ d_bias,
    ushort* __restrict__ wqkvb, float* __restrict__ bias_pre)
{
    const int bid = blockIdx.x;
    if (bid >= 32) {
        const int h = bid - 32;
        const float wd = w_disc[h] * LOG2E;
        const int j = h * T_SEQ + threadIdx.x * 8;
        const float4 a = *(const float4*)&d_bias[j];
        const float4 c = *(const float4*)&d_bias[j + 4];
        float4 oa, oc;
        oa.x = a.x * wd; oa.y = a.y * wd; oa.z = a.z * wd; oa.w = a.w * wd;
        oc.x = c.x * wd; oc.y = c.y * wd; oc.z = c.z * wd; oc.w = c.w * wd;
        *(float4*)&bias_pre[j] = oa;
        *(float4*)&bias_pre[j + 4] = oc;
        return;
    }
    const int qk = bid >> 4, h = bid & 15;
    const int e0 = threadIdx.x * 4;
    f32x4 acc[8];
    #pragma unroll
    for (int r = 0; r < 8; ++r) acc[r] = (f32x4){0.f, 0.f, 0.f, 0.f};
    for (int d = 0; d < 64; ++d) {
        const float4 xv = *(const float4*)&Wqkv[(size_t)(qk * 1024 + h * 64 + d) * 1024 + e0];
        #pragma unroll
        for (int r = 0; r < 8; ++r) {
            const float w = W_recip[d * 8 + r];
            acc[r][0] = fmaf(w, xv.x, acc[r][0]);
            acc[r][1] = fmaf(w, xv.y, acc[r][1]);
            acc[r][2] = fmaf(w, xv.z, acc[r][2]);
            acc[r][3] = fmaf(w, xv.w, acc[r][3]);
        }
    }
    #pragma unroll
    for (int r = 0; r < 8; ++r) {
        ushort4 o;
        o.x = f2b(acc[r][0]); o.y = f2b(acc[r][1]);
        o.z = f2b(acc[r][2]); o.w = f2b(acc[r][3]);
        *(ushort4*)&wqkvb[(size_t)(3072 + qk * 128 + h * 8 + r) * 1024 + e0] = o;
    }
}

// ---------------------------------------------------------------------------
// bf16 MFMA GEMM core (128x128 tile, 4 waves, global_load_lds staging).
// SMEM is one shared pool: Asl/Bsl live during the K-loop; callers may alias
// an epilogue buffer onto it (safe: the loop's final __syncthreads drains).
// ---------------------------------------------------------------------------
#define GEMM_CORE(Aptr, Bptr, KDIM, SMEMN)                                     \
    __shared__ __align__(16) ushort SMEM[SMEMN];                               \
    ushort* const Asl = SMEM;                                                  \
    ushort* const Bsl = SMEM + 4096;                                           \
    const int row0 = blockIdx.x * 128;                                         \
    const int col0 = blockIdx.y * 128;                                         \
    const int tid = threadIdx.x;                                               \
    const int wave = tid >> 6, lane = tid & 63;                                \
    const int wm = wave >> 1, wn = wave & 1;                                   \
    const int quad = lane >> 4, lq = lane & 15;                                \
    f32x4 acc[4][4];                                                           \
    _Pragma("unroll") for (int i = 0; i < 4; ++i)                              \
        _Pragma("unroll") for (int j = 0; j < 4; ++j)                          \
            acc[i][j] = (f32x4){0.f, 0.f, 0.f, 0.f};                           \
    for (int k0 = 0; k0 < (KDIM); k0 += 32) {                                  \
        _Pragma("unroll") for (int r2 = 0; r2 < 2; ++r2) {                     \
            const int c = r2 * 256 + tid;                                      \
            const int row = c >> 2, kc = (c & 3) * 8;                          \
            gl2lds16(&(Aptr)[(size_t)(row0 + row) * (KDIM) + k0 + kc], &Asl[c * 8]); \
            gl2lds16(&(Bptr)[(size_t)(col0 + row) * (KDIM) + k0 + kc], &Bsl[c * 8]); \
        }                                                                      \
        __syncthreads();                                                       \
        short8 af[4], bf[4];                                                   \
        _Pragma("unroll") for (int i = 0; i < 4; ++i)                          \
            af[i] = *(const short8*)&Asl[(wm * 64 + i * 16 + lq) * 32 + quad * 8]; \
        _Pragma("unroll") for (int j = 0; j < 4; ++j)                          \
            bf[j] = *(const short8*)&Bsl[(wn * 64 + j * 16 + lq) * 32 + quad * 8]; \
        _Pragma("unroll") for (int i = 0; i < 4; ++i)                          \
            _Pragma("unroll") for (int j = 0; j < 4; ++j)                      \
                acc[i][j] = __builtin_amdgcn_mfma_f32_16x16x32_bf16(           \
                    af[i], bf[j], acc[i][j], 0, 0, 0);                         \
        __syncthreads();                                                       \
    }

// Kernel 1: extended qkv GEMM, N=3328. 0.125*log2e attention scale folded
// into the q side (both main and k_low tail) so attn uses raw exp2.
__global__ __launch_bounds__(256, 4) void gemm_qkv_kernel(
    const ushort* __restrict__ A, const ushort* __restrict__ Bt,
    const float* __restrict__ w_std, const float* __restrict__ w_rec,
    ushort* __restrict__ qh, ushort* __restrict__ kh, ushort* __restrict__ vt)
{
    GEMM_CORE(A, Bt, 1024, 128 * 136)
    ushort* const Cs = SMEM;   // epilogue staging, overlays Asl/Bsl (safe)

    if (col0 >= 2048 && col0 < 3072) {
        // V region: vt[b][h][d][t], 4 consecutive t -> packed ushort4 store
        #pragma unroll
        for (int j = 0; j < 4; ++j) {
            const int cc = col0 + wn * 64 + j * 16 + lq;
            const int h = (cc >> 6) & 15;
            const int d = cc & 63;
            #pragma unroll
            for (int i = 0; i < 4; ++i) {
                const int rr0 = row0 + wm * 64 + i * 16 + quad * 4;
                const int b = rr0 >> 11, t0 = rr0 & 2047;
                ushort4 pv;
                pv.x = f2b(acc[i][j][0]); pv.y = f2b(acc[i][j][1]);
                pv.z = f2b(acc[i][j][2]); pv.w = f2b(acc[i][j][3]);
                *(ushort4*)&vt[((((size_t)b * NH + h) * HD + d) * T_SEQ + t0)] = pv;
            }
        }
    } else if (col0 < 2048) {
        // Q/K main: q scaled by w_std*0.125*log2e, k unscaled; d=0..55 only
        const bool isq = (col0 < 1024);
        #pragma unroll
        for (int j = 0; j < 4; ++j) {
            const int colc = wn * 64 + j * 16 + lq;
            const int h = ((col0 + colc) >> 6) & 15;
            const float sc = isq ? w_std[h] * (0.125f * LOG2E) : 1.0f;
            #pragma unroll
            for (int i = 0; i < 4; ++i)
                #pragma unroll
                for (int r = 0; r < 4; ++r)
                    Cs[(wm * 64 + i * 16 + quad * 4 + r) * 136 + colc] =
                        f2b(acc[i][j][r] * sc);
        }
        __syncthreads();
        ushort* dst = isq ? qh : kh;
        const int hbase = (col0 >> 6) & 15;
        #pragma unroll
        for (int rep = 0; rep < 8; ++rep) {
            const int id = rep * 256 + tid;
            const int row = id >> 4, chunk = id & 15;
            if ((chunk & 7) == 7) continue;   // d=56..63 owned by tail blocks
            const int h = hbase + (chunk >> 3);
            const int d = (chunk & 7) * 8;
            const int rr = row0 + row;
            const int b = rr >> 11, t = rr & 2047;
            const uint4 val = *(const uint4*)&Cs[row * 136 + chunk * 8];
            *(uint4*)&dst[((((size_t)b * NH + h) * T_SEQ + t) * HD + d)] = val;
        }
    } else {
        // Tail: q_low -> kh tails (unscaled); k_low -> qh tails (w_rec*0.125*log2e)
        const bool isqlow = (col0 < 3200);
        #pragma unroll
        for (int j = 0; j < 4; ++j) {
            const int colc = wn * 64 + j * 16 + lq;
            const int h = colc >> 3;
            const float sc = isqlow ? 1.0f : w_rec[h] * (0.125f * LOG2E);
            #pragma unroll
            for (int i = 0; i < 4; ++i)
                #pragma unroll
                for (int r = 0; r < 4; ++r)
                    Cs[(wm * 64 + i * 16 + quad * 4 + r) * 136 + colc] =
                        f2b(acc[i][j][r] * sc);
        }
        __syncthreads();
        ushort* dst = isqlow ? kh : qh;
        #pragma unroll
        for (int rep = 0; rep < 8; ++rep) {
            const int id = rep * 256 + tid;
            const int row = id >> 4, h = id & 15;
            const int rr = row0 + row;
            const int b = rr >> 11, t = rr & 2047;
            const uint4 val = *(const uint4*)&Cs[row * 136 + h * 8];
            *(uint4*)&dst[((((size_t)b * NH + h) * T_SEQ + t) * HD + 56)] = val;
        }
    }
}

// Kernel 4: out(f32) = ao @ Wproj^T.
__global__ __launch_bounds__(256) void gemm_proj_kernel(
    const ushort* __restrict__ A, const ushort* __restrict__ Bt,
    float* __restrict__ C)
{
    GEMM_CORE(A, Bt, 1024, 8192)
    #pragma unroll
    for (int i = 0; i < 4; ++i) {
        #pragma unroll
        for (int r = 0; r < 4; ++r) {
            const int rr = row0 + wm * 64 + i * 16 + quad * 4 + r;
            #pragma unroll
            for (int j = 0; j < 4; ++j) {
                const int cc = col0 + wn * 64 + j * 16 + lq;
                C[(size_t)rr * 1024 + cc] = acc[i][j][r];
            }
        }
    }
}

// ---------------------------------------------------------------------------
// Kernel 3: MFMA attention, transposed formulation.
//   S^T = mfma(K, Q): lane holds 4 consecutive keys of one q-row
//   O^T = mfma(V, P): lane holds 4 consecutive d of one q-row
// Q/K/V staged via global_load_lds with pre-swizzled global source
// (XOR of the 16B slot with row&7 / row&15); fragment reads use the same
// row-dependent XOR -> conflict-free. P (bf16, packed via v_perm) overlays
// the K buffer; rows are wave-private. exp2 with all scales pre-folded.
// ---------------------------------------------------------------------------
__global__ __launch_bounds__(256, 4) void attn_kernel(
    const ushort* __restrict__ qa, const ushort* __restrict__ ka,
    const ushort* __restrict__ vt, const float* __restrict__ bias_pre,
    ushort* __restrict__ out)
{
    __shared__ __align__(16) ushort Qs[64 * 64];     //  8 KiB
    __shared__ __align__(16) ushort KPs[128 * 64];   // 16 KiB: K tile, then P[64][128]
    __shared__ __align__(16) ushort Vs[64 * 128];    // 16 KiB
    const int bh = blockIdx.x;
    const int qt = 31 - blockIdx.y;
    const int h = bh & 15;
    const int b = bh >> 4;
    const int tid = threadIdx.x;
    const int wave = tid >> 6, lane = tid & 63;
    const int quad = lane >> 4, lq = lane & 15;
    const int l7 = lq & 7;
    const size_t base = (size_t)bh * T_SEQ * HD;

    // Q stage (once), swizzled source -> linear LDS
    #pragma unroll
    for (int rep = 0; rep < 2; ++rep) {
        const int idx = rep * 256 + tid;
        const int row = idx >> 3, slot = idx & 7;
        gl2lds16(&qa[base + (size_t)(qt * 64 + row) * 64 + ((slot ^ (row & 7)) << 3)],
                 &Qs[idx * 8]);
    }
    __syncthreads();
    short8 bq[2];
    #pragma unroll
    for (int ks = 0; ks < 2; ++ks)
        bq[ks] = *(const short8*)&Qs[(wave * 16 + lq) * 64 + (((ks * 4 + quad) ^ l7) << 3)];

    f32x4 o4[4];
    #pragma unroll
    for (int dt = 0; dt < 4; ++dt) o4[dt] = (f32x4){0.f, 0.f, 0.f, 0.f};
    float lsum = 0.f;
    const int qrow = qt * 64 + wave * 16 + lq;
    const int prow = (wave * 16 + lq) * 128;
    const int nchunks = (qt + 2) >> 1;
    const float* bias_h = &bias_pre[h * T_SEQ];

    for (int c = 0; c < nchunks; ++c) {
        const int k0 = c * 128;
        if (c) __syncthreads();   // prev chunk's P/V reads done before restage
        #pragma unroll
        for (int rep = 0; rep < 4; ++rep) {
            const int idx = rep * 256 + tid;
            const int row = idx >> 3, slot = idx & 7;
            gl2lds16(&ka[base + (size_t)(k0 + row) * 64 + ((slot ^ (row & 7)) << 3)],
                     &KPs[idx * 8]);
        }
        #pragma unroll
        for (int rep = 0; rep < 4; ++rep) {
            const int idx = rep * 256 + tid;
            const int row = idx >> 4, slot = idx & 15;
            gl2lds16(&vt[base + (size_t)row * T_SEQ + k0 + ((slot ^ (row & 15)) << 3)],
                     &Vs[idx * 8]);
        }
        __syncthreads();

        // S^T accumulators init with prescaled bias (rows = keys), then K·Q^T
        f32x4 s4[8];
        #pragma unroll
        for (int nt = 0; nt < 8; ++nt)
            s4[nt] = *(const f32x4*)&bias_h[k0 + nt * 16 + quad * 4];
        #pragma unroll
        for (int ks = 0; ks < 2; ++ks)
            #pragma unroll
            for (int nt = 0; nt < 8; ++nt) {
                const short8 ak = *(const short8*)
                    &KPs[(nt * 16 + lq) * 64 + (((ks * 4 + quad) ^ l7) << 3)];
                s4[nt] = __builtin_amdgcn_mfma_f32_16x16x32_bf16(
                    ak, bq[ks], s4[nt], 0, 0, 0);
            }
        __syncthreads();   // all waves done reading K -> P may overwrite

        const bool lastc = (c == nchunks - 1);
        #pragma unroll
        for (int nt = 0; nt < 8; ++nt) {
            f32x4 sv = s4[nt];
            if (lastc) {
                const int kb = k0 + nt * 16 + quad * 4;
                #pragma unroll
                for (int r = 0; r < 4; ++r)
                    if (kb + r > qrow) sv[r] = NEGINF;
            }
            const float p0 = EXP2(sv[0]), p1 = EXP2(sv[1]);
            const float p2 = EXP2(sv[2]), p3 = EXP2(sv[3]);
            lsum += (p0 + p1) + (p2 + p3);
            const int pcol = (nt * 16 + quad * 4) ^ (l7 << 3);
            uint2 pv; pv.x = pack_bf16(p0, p1); pv.y = pack_bf16(p2, p3);
            *(uint2*)&KPs[prow + pcol] = pv;
        }
        // P rows are wave-private: same-wave DS ordering suffices, no barrier

        #pragma unroll
        for (int ks = 0; ks < 4; ++ks) {
            const short8 bp = *(const short8*)
                &KPs[prow + ((ks * 32 + quad * 8) ^ (l7 << 3))];
            #pragma unroll
            for (int dt = 0; dt < 4; ++dt) {
                const short8 av = *(const short8*)
                    &Vs[(dt * 16 + lq) * 128 + (((ks * 4 + quad) ^ lq) << 3)];
                o4[dt] = __builtin_amdgcn_mfma_f32_16x16x32_bf16(
                    av, bp, o4[dt], 0, 0, 0);
            }
        }
    }

    // row sum: lanes {lq, lq+16, lq+32, lq+48} hold disjoint key subsets
    lsum += __shfl_xor(lsum, 16, 64);
    lsum += __shfl_xor(lsum, 32, 64);
    const float inv = 1.0f / lsum;
    const size_t obase = ((size_t)b * T_SEQ + qrow) * CEMB + h * HD;
    #pragma unroll
    for (int dt = 0; dt < 4; ++dt) {
        ushort4 ov;
        ov.x = f2b_fast(o4[dt][0] * inv);
        ov.y = f2b_fast(o4[dt][1] * inv);
        ov.z = f2b_fast(o4[dt][2] * inv);
        ov.w = f2b_fast(o4[dt][3] * inv);
        *(ushort4*)&out[obase + dt * 16 + quad * 4] = ov;
    }
}

// ---------------------------------------------------------------------------
extern "C" void kernel_launch(void* const* d_in, const int* in_sizes, int n_in,
                              void* d_out, int out_size, void* d_ws, size_t ws_size,
                              hipStream_t stream) {
    const float* x       = (const float*)d_in[0];
    const float* Wqkv    = (const float*)d_in[1];
    const float* Wproj   = (const float*)d_in[2];
    const float* W_recip = (const float*)d_in[3];
    const float* w_std   = (const float*)d_in[4];
    const float* w_rec   = (const float*)d_in[5];
    const float* w_disc  = (const float*)d_in[6];
    const float* d_bias  = (const float*)d_in[7];
    float* out = (float*)d_out;

    const size_t NX = (size_t)4096 * 1024;
    const size_t NWQKVX = (size_t)3328 * 1024;
    const size_t NWPROJ = (size_t)1024 * 1024;
    ushort* xb     = (ushort*)d_ws;
    ushort* wqkvb  = xb + NX;
    ushort* wprojb = wqkvb + NWQKVX;
    ushort* qh     = wprojb + NWPROJ;
    ushort* kh     = qh + NX;
    ushort* vt     = kh + NX;
    ushort* ao     = vt + NX;
    float*  bias_pre = (float*)(ao + NX);   // 16*2048 f32 = 128 KiB

    convert_all_kernel<<<8192, 256, 0, stream>>>(x, Wqkv, Wproj, xb, wqkvb, wprojb);
    wlow_kernel<<<48, 256, 0, stream>>>(Wqkv, W_recip, w_disc, d_bias, wqkvb, bias_pre);
    gemm_qkv_kernel<<<dim3(32, 26), 256, 0, stream>>>(xb, wqkvb, w_std, w_rec, qh, kh, vt);
    attn_kernel<<<dim3(32, 32), 256, 0, stream>>>(qh, kh, vt, bias_pre, ao);
    gemm_proj_kernel<<<dim3(32, 8), 256, 0, stream>>>(ao, wprojb, out);
}

// Round 2
// 191.844 us; speedup vs baseline: 1.1587x; 1.0990x over previous
//
#include <hip/hip_runtime.h>
#include <math.h>

#define T_SEQ 2048
#define NH 16
#define HD 64
#define CEMB 1024
#define NEGINF -3.0e38f
#define LOG2E 1.4426950408889634f

typedef unsigned short ushort;
typedef unsigned int uint;
typedef __attribute__((ext_vector_type(8))) short short8;
typedef __attribute__((ext_vector_type(4))) float f32x4;

#if __has_builtin(__builtin_amdgcn_exp2f)
#define EXP2(x) __builtin_amdgcn_exp2f(x)
#else
#define EXP2(x) exp2f(x)
#endif

__device__ __forceinline__ float b2f(ushort h) {
    union { uint u; float f; } cv; cv.u = ((uint)h) << 16; return cv.f;
}
__device__ __forceinline__ ushort f2b(float f) {
    union { float f; uint u; } cv; cv.f = f;
    return (ushort)((cv.u + 0x7FFF + ((cv.u >> 16) & 1)) >> 16);
}
__device__ __forceinline__ ushort f2b_fast(float f) {   // round-half-up, 2 ops
    union { float f; uint u; } cv; cv.f = f;
    return (ushort)((cv.u + 0x8000) >> 16);
}
// pack two f32 -> packed bf16 pair (round-half-up) with one v_perm_b32
__device__ __forceinline__ uint pack_bf16(float a, float b) {
    union { float f; uint u; } ua, ub; ua.f = a; ub.f = b;
    return __builtin_amdgcn_perm(ub.u + 0x8000u, ua.u + 0x8000u, 0x07060302u);
}
__device__ __forceinline__ void gl2lds16(const ushort* g, ushort* l) {
    __builtin_amdgcn_global_load_lds(
        (const __attribute__((address_space(1))) void*)g,
        (__attribute__((address_space(3))) void*)l, 16, 0, 0);
}

// ---------------------------------------------------------------------------
// prep: merged f32->bf16 convert for x/Wqkv/Wproj + Wlow rows + bias_pre.
//   blocks [0,8192)    : bulk convert
//   blocks [8192,8224) : Wlow = Wqkv[q|k block] @ W_recip -> wqkvb rows 3072+
//   blocks [8224,8240) : bias_pre[h][t] = w_disc[h]*log2e*d_bias[h][t]
// ---------------------------------------------------------------------------
__global__ __launch_bounds__(256) void prep_kernel(
    const float* __restrict__ x, const float* __restrict__ Wqkv,
    const float* __restrict__ Wproj, const float* __restrict__ W_recip,
    const float* __restrict__ w_disc, const float* __restrict__ d_bias,
    ushort* __restrict__ xb, ushort* __restrict__ wqkvb,
    ushort* __restrict__ wprojb, float* __restrict__ bias_pre)
{
    const int bid = blockIdx.x;
    if (bid < 8192) {
        const float* src; ushort* dst; int off;
        if (bid < 4096)      { src = x;     dst = xb;     off = bid; }
        else if (bid < 7168) { src = Wqkv;  dst = wqkvb;  off = bid - 4096; }
        else                 { src = Wproj; dst = wprojb; off = bid - 7168; }
        const int i = (off * 256 + threadIdx.x) * 4;
        const float4 v = *(const float4*)&src[i];
        ushort4 o;
        o.x = f2b(v.x); o.y = f2b(v.y); o.z = f2b(v.z); o.w = f2b(v.w);
        *(ushort4*)&dst[i] = o;
        return;
    }
    if (bid >= 8224) {
        const int h = bid - 8224;
        const float wd = w_disc[h] * LOG2E;
        const int j = h * T_SEQ + threadIdx.x * 8;
        const float4 a = *(const float4*)&d_bias[j];
        const float4 c = *(const float4*)&d_bias[j + 4];
        float4 oa, oc;
        oa.x = a.x * wd; oa.y = a.y * wd; oa.z = a.z * wd; oa.w = a.w * wd;
        oc.x = c.x * wd; oc.y = c.y * wd; oc.z = c.z * wd; oc.w = c.w * wd;
        *(float4*)&bias_pre[j] = oa;
        *(float4*)&bias_pre[j + 4] = oc;
        return;
    }
    const int wb = bid - 8192;
    const int qk = wb >> 4, h = wb & 15;
    const int e0 = threadIdx.x * 4;
    f32x4 acc[8];
    #pragma unroll
    for (int r = 0; r < 8; ++r) acc[r] = (f32x4){0.f, 0.f, 0.f, 0.f};
    #pragma unroll 4
    for (int d = 0; d < 64; ++d) {
        const float4 xv = *(const float4*)&Wqkv[(size_t)(qk * 1024 + h * 64 + d) * 1024 + e0];
        #pragma unroll
        for (int r = 0; r < 8; ++r) {
            const float w = W_recip[d * 8 + r];
            acc[r][0] = fmaf(w, xv.x, acc[r][0]);
            acc[r][1] = fmaf(w, xv.y, acc[r][1]);
            acc[r][2] = fmaf(w, xv.z, acc[r][2]);
            acc[r][3] = fmaf(w, xv.w, acc[r][3]);
        }
    }
    #pragma unroll
    for (int r = 0; r < 8; ++r) {
        ushort4 o;
        o.x = f2b(acc[r][0]); o.y = f2b(acc[r][1]);
        o.z = f2b(acc[r][2]); o.w = f2b(acc[r][3]);
        *(ushort4*)&wqkvb[(size_t)(3072 + qk * 128 + h * 8 + r) * 1024 + e0] = o;
    }
}

// ---------------------------------------------------------------------------
// bf16 MFMA GEMM core (128x128 tile, BK=64, 4 waves, global_load_lds staging,
// XOR-swizzled LDS: slot ^= row&7 on both the staging source and the
// fragment reads -> ds_read_b128 at minimal 2-way bank aliasing).
// SMEM is one shared pool: Asl/Bsl (32 KiB) live during the K-loop; callers
// may alias an epilogue buffer onto it (the loop's final barrier drains).
// ---------------------------------------------------------------------------
#define GEMM_CORE(Aptr, Bptr, KDIM, SMEMN)                                     \
    __shared__ __align__(16) ushort SMEM[SMEMN];                               \
    ushort* const Asl = SMEM;                                                  \
    ushort* const Bsl = SMEM + 8192;                                           \
    const int row0 = blockIdx.x * 128;                                         \
    const int col0 = blockIdx.y * 128;                                         \
    const int tid = threadIdx.x;                                               \
    const int wave = tid >> 6, lane = tid & 63;                                \
    const int wm = wave >> 1, wn = wave & 1;                                   \
    const int quad = lane >> 4, lq = lane & 15;                                \
    const int l7 = lq & 7;                                                     \
    f32x4 acc[4][4];                                                           \
    _Pragma("unroll") for (int i = 0; i < 4; ++i)                              \
        _Pragma("unroll") for (int j = 0; j < 4; ++j)                          \
            acc[i][j] = (f32x4){0.f, 0.f, 0.f, 0.f};                           \
    for (int k0 = 0; k0 < (KDIM); k0 += 64) {                                  \
        _Pragma("unroll") for (int p = 0; p < 4; ++p) {                        \
            const int idx = p * 256 + tid;                                     \
            const int row = idx >> 3, slot = idx & 7;                          \
            const int kc = (slot ^ (row & 7)) << 3;                            \
            gl2lds16(&(Aptr)[(size_t)(row0 + row) * (KDIM) + k0 + kc], &Asl[idx * 8]); \
            gl2lds16(&(Bptr)[(size_t)(col0 + row) * (KDIM) + k0 + kc], &Bsl[idx * 8]); \
        }                                                                      \
        __syncthreads();                                                       \
        _Pragma("unroll") for (int ks = 0; ks < 2; ++ks) {                     \
            short8 af[4], bf[4];                                               \
            _Pragma("unroll") for (int i = 0; i < 4; ++i)                      \
                af[i] = *(const short8*)&Asl[(wm * 64 + i * 16 + lq) * 64 +    \
                                             (((ks * 4 + quad) ^ l7) << 3)];   \
            _Pragma("unroll") for (int j = 0; j < 4; ++j)                      \
                bf[j] = *(const short8*)&Bsl[(wn * 64 + j * 16 + lq) * 64 +    \
                                             (((ks * 4 + quad) ^ l7) << 3)];   \
            _Pragma("unroll") for (int i = 0; i < 4; ++i)                      \
                _Pragma("unroll") for (int j = 0; j < 4; ++j)                  \
                    acc[i][j] = __builtin_amdgcn_mfma_f32_16x16x32_bf16(       \
                        af[i], bf[j], acc[i][j], 0, 0, 0);                     \
        }                                                                      \
        __syncthreads();                                                       \
    }

// Kernel 1: extended qkv GEMM, N=3328. 0.125*log2e attention scale folded
// into the q side (both main and k_low tail) so attn uses raw exp2.
__global__ __launch_bounds__(256, 4) void gemm_qkv_kernel(
    const ushort* __restrict__ A, const ushort* __restrict__ Bt,
    const float* __restrict__ w_std, const float* __restrict__ w_rec,
    ushort* __restrict__ qh, ushort* __restrict__ kh, ushort* __restrict__ vt)
{
    GEMM_CORE(A, Bt, 1024, 128 * 136)
    ushort* const Cs = SMEM;   // epilogue staging, overlays Asl/Bsl (safe)

    if (col0 >= 2048 && col0 < 3072) {
        // V region: vt[b][h][d][t], 4 consecutive t -> packed ushort4 store
        #pragma unroll
        for (int j = 0; j < 4; ++j) {
            const int cc = col0 + wn * 64 + j * 16 + lq;
            const int h = (cc >> 6) & 15;
            const int d = cc & 63;
            #pragma unroll
            for (int i = 0; i < 4; ++i) {
                const int rr0 = row0 + wm * 64 + i * 16 + quad * 4;
                const int b = rr0 >> 11, t0 = rr0 & 2047;
                ushort4 pv;
                pv.x = f2b(acc[i][j][0]); pv.y = f2b(acc[i][j][1]);
                pv.z = f2b(acc[i][j][2]); pv.w = f2b(acc[i][j][3]);
                *(ushort4*)&vt[((((size_t)b * NH + h) * HD + d) * T_SEQ + t0)] = pv;
            }
        }
    } else if (col0 < 2048) {
        // Q/K main: q scaled by w_std*0.125*log2e, k unscaled; d=0..55 only
        const bool isq = (col0 < 1024);
        #pragma unroll
        for (int j = 0; j < 4; ++j) {
            const int colc = wn * 64 + j * 16 + lq;
            const int h = ((col0 + colc) >> 6) & 15;
            const float sc = isq ? w_std[h] * (0.125f * LOG2E) : 1.0f;
            #pragma unroll
            for (int i = 0; i < 4; ++i)
                #pragma unroll
                for (int r = 0; r < 4; ++r)
                    Cs[(wm * 64 + i * 16 + quad * 4 + r) * 136 + colc] =
                        f2b(acc[i][j][r] * sc);
        }
        __syncthreads();
        ushort* dst = isq ? qh : kh;
        const int hbase = (col0 >> 6) & 15;
        #pragma unroll
        for (int rep = 0; rep < 8; ++rep) {
            const int id = rep * 256 + tid;
            const int row = id >> 4, chunk = id & 15;
            if ((chunk & 7) == 7) continue;   // d=56..63 owned by tail blocks
            const int h = hbase + (chunk >> 3);
            const int d = (chunk & 7) * 8;
            const int rr = row0 + row;
            const int b = rr >> 11, t = rr & 2047;
            const uint4 val = *(const uint4*)&Cs[row * 136 + chunk * 8];
            *(uint4*)&dst[((((size_t)b * NH + h) * T_SEQ + t) * HD + d)] = val;
        }
    } else {
        // Tail: q_low -> kh tails (unscaled); k_low -> qh tails (w_rec*0.125*log2e)
        const bool isqlow = (col0 < 3200);
        #pragma unroll
        for (int j = 0; j < 4; ++j) {
            const int colc = wn * 64 + j * 16 + lq;
            const int h = colc >> 3;
            const float sc = isqlow ? 1.0f : w_rec[h] * (0.125f * LOG2E);
            #pragma unroll
            for (int i = 0; i < 4; ++i)
                #pragma unroll
                for (int r = 0; r < 4; ++r)
                    Cs[(wm * 64 + i * 16 + quad * 4 + r) * 136 + colc] =
                        f2b(acc[i][j][r] * sc);
        }
        __syncthreads();
        ushort* dst = isqlow ? kh : qh;
        #pragma unroll
        for (int rep = 0; rep < 8; ++rep) {
            const int id = rep * 256 + tid;
            const int row = id >> 4, h = id & 15;
            const int rr = row0 + row;
            const int b = rr >> 11, t = rr & 2047;
            const uint4 val = *(const uint4*)&Cs[row * 136 + h * 8];
            *(uint4*)&dst[((((size_t)b * NH + h) * T_SEQ + t) * HD + 56)] = val;
        }
    }
}

// Kernel 4: out(f32) = ao @ Wproj^T.
__global__ __launch_bounds__(256, 4) void gemm_proj_kernel(
    const ushort* __restrict__ A, const ushort* __restrict__ Bt,
    float* __restrict__ C)
{
    GEMM_CORE(A, Bt, 1024, 16384)
    #pragma unroll
    for (int i = 0; i < 4; ++i) {
        #pragma unroll
        for (int r = 0; r < 4; ++r) {
            const int rr = row0 + wm * 64 + i * 16 + quad * 4 + r;
            #pragma unroll
            for (int j = 0; j < 4; ++j) {
                const int cc = col0 + wn * 64 + j * 16 + lq;
                C[(size_t)rr * 1024 + cc] = acc[i][j][r];
            }
        }
    }
}

// ---------------------------------------------------------------------------
// Kernel 3: MFMA attention, transposed formulation.
//   S^T = mfma(K, Q): lane holds 4 consecutive keys of one q-row
//   O^T = mfma(V, P): lane holds 4 consecutive d of one q-row
// Q/K/V staged via global_load_lds with pre-swizzled global source
// (XOR of the 16B slot with row&7 / row&15); fragment reads use the same
// row-dependent XOR -> conflict-free. P (bf16, packed via v_perm) overlays
// the K buffer; rows are wave-private. exp2 with all scales pre-folded.
// ---------------------------------------------------------------------------
__global__ __launch_bounds__(256, 4) void attn_kernel(
    const ushort* __restrict__ qa, const ushort* __restrict__ ka,
    const ushort* __restrict__ vt, const float* __restrict__ bias_pre,
    ushort* __restrict__ out)
{
    __shared__ __align__(16) ushort Qs[64 * 64];     //  8 KiB
    __shared__ __align__(16) ushort KPs[128 * 64];   // 16 KiB: K tile, then P[64][128]
    __shared__ __align__(16) ushort Vs[64 * 128];    // 16 KiB
    const int bh = blockIdx.x;
    const int qt = 31 - blockIdx.y;
    const int h = bh & 15;
    const int b = bh >> 4;
    const int tid = threadIdx.x;
    const int wave = tid >> 6, lane = tid & 63;
    const int quad = lane >> 4, lq = lane & 15;
    const int l7 = lq & 7;
    const size_t base = (size_t)bh * T_SEQ * HD;

    // Q stage (once), swizzled source -> linear LDS
    #pragma unroll
    for (int rep = 0; rep < 2; ++rep) {
        const int idx = rep * 256 + tid;
        const int row = idx >> 3, slot = idx & 7;
        gl2lds16(&qa[base + (size_t)(qt * 64 + row) * 64 + ((slot ^ (row & 7)) << 3)],
                 &Qs[idx * 8]);
    }
    __syncthreads();
    short8 bq[2];
    #pragma unroll
    for (int ks = 0; ks < 2; ++ks)
        bq[ks] = *(const short8*)&Qs[(wave * 16 + lq) * 64 + (((ks * 4 + quad) ^ l7) << 3)];

    f32x4 o4[4];
    #pragma unroll
    for (int dt = 0; dt < 4; ++dt) o4[dt] = (f32x4){0.f, 0.f, 0.f, 0.f};
    float lsum = 0.f;
    const int qrow = qt * 64 + wave * 16 + lq;
    const int prow = (wave * 16 + lq) * 128;
    const int nchunks = (qt + 2) >> 1;
    const float* bias_h = &bias_pre[h * T_SEQ];

    for (int c = 0; c < nchunks; ++c) {
        const int k0 = c * 128;
        if (c) __syncthreads();   // prev chunk's P/V reads done before restage
        #pragma unroll
        for (int rep = 0; rep < 4; ++rep) {
            const int idx = rep * 256 + tid;
            const int row = idx >> 3, slot = idx & 7;
            gl2lds16(&ka[base + (size_t)(k0 + row) * 64 + ((slot ^ (row & 7)) << 3)],
                     &KPs[idx * 8]);
        }
        #pragma unroll
        for (int rep = 0; rep < 4; ++rep) {
            const int idx = rep * 256 + tid;
            const int row = idx >> 4, slot = idx & 15;
            gl2lds16(&vt[base + (size_t)row * T_SEQ + k0 + ((slot ^ (row & 15)) << 3)],
                     &Vs[idx * 8]);
        }
        __syncthreads();

        // S^T accumulators init with prescaled bias (rows = keys), then K·Q^T
        f32x4 s4[8];
        #pragma unroll
        for (int nt = 0; nt < 8; ++nt)
            s4[nt] = *(const f32x4*)&bias_h[k0 + nt * 16 + quad * 4];
        #pragma unroll
        for (int ks = 0; ks < 2; ++ks)
            #pragma unroll
            for (int nt = 0; nt < 8; ++nt) {
                const short8 ak = *(const short8*)
                    &KPs[(nt * 16 + lq) * 64 + (((ks * 4 + quad) ^ l7) << 3)];
                s4[nt] = __builtin_amdgcn_mfma_f32_16x16x32_bf16(
                    ak, bq[ks], s4[nt], 0, 0, 0);
            }
        __syncthreads();   // all waves done reading K -> P may overwrite

        const bool lastc = (c == nchunks - 1);
        #pragma unroll
        for (int nt = 0; nt < 8; ++nt) {
            f32x4 sv = s4[nt];
            if (lastc) {
                const int kb = k0 + nt * 16 + quad * 4;
                #pragma unroll
                for (int r = 0; r < 4; ++r)
                    if (kb + r > qrow) sv[r] = NEGINF;
            }
            const float p0 = EXP2(sv[0]), p1 = EXP2(sv[1]);
            const float p2 = EXP2(sv[2]), p3 = EXP2(sv[3]);
            lsum += (p0 + p1) + (p2 + p3);
            const int pcol = (nt * 16 + quad * 4) ^ (l7 << 3);
            uint2 pv; pv.x = pack_bf16(p0, p1); pv.y = pack_bf16(p2, p3);
            *(uint2*)&KPs[prow + pcol] = pv;
        }
        // P rows are wave-private: same-wave DS ordering suffices, no barrier

        #pragma unroll
        for (int ks = 0; ks < 4; ++ks) {
            const short8 bp = *(const short8*)
                &KPs[prow + ((ks * 32 + quad * 8) ^ (l7 << 3))];
            #pragma unroll
            for (int dt = 0; dt < 4; ++dt) {
                const short8 av = *(const short8*)
                    &Vs[(dt * 16 + lq) * 128 + (((ks * 4 + quad) ^ lq) << 3)];
                o4[dt] = __builtin_amdgcn_mfma_f32_16x16x32_bf16(
                    av, bp, o4[dt], 0, 0, 0);
            }
        }
    }

    // row sum: lanes {lq, lq+16, lq+32, lq+48} hold disjoint key subsets
    lsum += __shfl_xor(lsum, 16, 64);
    lsum += __shfl_xor(lsum, 32, 64);
    const float inv = 1.0f / lsum;
    const size_t obase = ((size_t)b * T_SEQ + qrow) * CEMB + h * HD;
    #pragma unroll
    for (int dt = 0; dt < 4; ++dt) {
        ushort4 ov;
        ov.x = f2b_fast(o4[dt][0] * inv);
        ov.y = f2b_fast(o4[dt][1] * inv);
        ov.z = f2b_fast(o4[dt][2] * inv);
        ov.w = f2b_fast(o4[dt][3] * inv);
        *(ushort4*)&out[obase + dt * 16 + quad * 4] = ov;
    }
}

// ---------------------------------------------------------------------------
extern "C" void kernel_launch(void* const* d_in, const int* in_sizes, int n_in,
                              void* d_out, int out_size, void* d_ws, size_t ws_size,
                              hipStream_t stream) {
    const float* x       = (const float*)d_in[0];
    const float* Wqkv    = (const float*)d_in[1];
    const float* Wproj   = (const float*)d_in[2];
    const float* W_recip = (const float*)d_in[3];
    const float* w_std   = (const float*)d_in[4];
    const float* w_rec   = (const float*)d_in[5];
    const float* w_disc  = (const float*)d_in[6];
    const float* d_bias  = (const float*)d_in[7];
    float* out = (float*)d_out;

    const size_t NX = (size_t)4096 * 1024;
    const size_t NWQKVX = (size_t)3328 * 1024;
    const size_t NWPROJ = (size_t)1024 * 1024;
    ushort* xb     = (ushort*)d_ws;
    ushort* wqkvb  = xb + NX;
    ushort* wprojb = wqkvb + NWQKVX;
    ushort* qh     = wprojb + NWPROJ;
    ushort* kh     = qh + NX;
    ushort* vt     = kh + NX;
    ushort* ao     = vt + NX;
    float*  bias_pre = (float*)(ao + NX);   // 16*2048 f32 = 128 KiB

    prep_kernel<<<8240, 256, 0, stream>>>(x, Wqkv, Wproj, W_recip, w_disc, d_bias,
                                          xb, wqkvb, wprojb, bias_pre);
    gemm_qkv_kernel<<<dim3(32, 26), 256, 0, stream>>>(xb, wqkvb, w_std, w_rec, qh, kh, vt);
    attn_kernel<<<dim3(32, 32), 256, 0, stream>>>(qh, kh, vt, bias_pre, ao);
    gemm_proj_kernel<<<dim3(32, 8), 256, 0, stream>>>(ao, wprojb, out);
}

// Round 3
// 190.710 us; speedup vs baseline: 1.1656x; 1.0059x over previous
//
#include <hip/hip_runtime.h>
#include <math.h>

#define T_SEQ 2048
#define NH 16
#define HD 64
#define CEMB 1024
#define NEGINF -3.0e38f
#define LOG2E 1.4426950408889634f

typedef unsigned short ushort;
typedef unsigned int uint;
typedef __attribute__((ext_vector_type(8))) short short8;
typedef __attribute__((ext_vector_type(4))) float f32x4;

#if __has_builtin(__builtin_amdgcn_exp2f)
#define EXP2(x) __builtin_amdgcn_exp2f(x)
#else
#define EXP2(x) exp2f(x)
#endif

__device__ __forceinline__ float b2f(ushort h) {
    union { uint u; float f; } cv; cv.u = ((uint)h) << 16; return cv.f;
}
__device__ __forceinline__ ushort f2b(float f) {
    union { float f; uint u; } cv; cv.f = f;
    return (ushort)((cv.u + 0x7FFF + ((cv.u >> 16) & 1)) >> 16);
}
__device__ __forceinline__ ushort f2b_fast(float f) {   // round-half-up, 2 ops
    union { float f; uint u; } cv; cv.f = f;
    return (ushort)((cv.u + 0x8000) >> 16);
}
// pack two f32 -> packed bf16 pair (round-half-up) with one v_perm_b32
__device__ __forceinline__ uint pack_bf16(float a, float b) {
    union { float f; uint u; } ua, ub; ua.f = a; ub.f = b;
    return __builtin_amdgcn_perm(ub.u + 0x8000u, ua.u + 0x8000u, 0x07060302u);
}
__device__ __forceinline__ void gl2lds16(const ushort* g, ushort* l) {
    __builtin_amdgcn_global_load_lds(
        (const __attribute__((address_space(1))) void*)g,
        (__attribute__((address_space(3))) void*)l, 16, 0, 0);
}

// ---------------------------------------------------------------------------
// prep: merged f32->bf16 convert for x/Wqkv/Wproj + Wlow rows + bias_pre.
//   blocks [0,8192)    : bulk convert
//   blocks [8192,8224) : Wlow = Wqkv[q|k block] @ W_recip -> wqkvb rows 3072+
//   blocks [8224,8240) : bias_pre[h][t] = w_disc[h]*log2e*d_bias[h][t]
// ---------------------------------------------------------------------------
__global__ __launch_bounds__(256) void prep_kernel(
    const float* __restrict__ x, const float* __restrict__ Wqkv,
    const float* __restrict__ Wproj, const float* __restrict__ W_recip,
    const float* __restrict__ w_disc, const float* __restrict__ d_bias,
    ushort* __restrict__ xb, ushort* __restrict__ wqkvb,
    ushort* __restrict__ wprojb, float* __restrict__ bias_pre)
{
    const int bid = blockIdx.x;
    if (bid < 8192) {
        const float* src; ushort* dst; int off;
        if (bid < 4096)      { src = x;     dst = xb;     off = bid; }
        else if (bid < 7168) { src = Wqkv;  dst = wqkvb;  off = bid - 4096; }
        else                 { src = Wproj; dst = wprojb; off = bid - 7168; }
        const int i = (off * 256 + threadIdx.x) * 4;
        const float4 v = *(const float4*)&src[i];
        ushort4 o;
        o.x = f2b(v.x); o.y = f2b(v.y); o.z = f2b(v.z); o.w = f2b(v.w);
        *(ushort4*)&dst[i] = o;
        return;
    }
    if (bid >= 8224) {
        const int h = bid - 8224;
        const float wd = w_disc[h] * LOG2E;
        const int j = h * T_SEQ + threadIdx.x * 8;
        const float4 a = *(const float4*)&d_bias[j];
        const float4 c = *(const float4*)&d_bias[j + 4];
        float4 oa, oc;
        oa.x = a.x * wd; oa.y = a.y * wd; oa.z = a.z * wd; oa.w = a.w * wd;
        oc.x = c.x * wd; oc.y = c.y * wd; oc.z = c.z * wd; oc.w = c.w * wd;
        *(float4*)&bias_pre[j] = oa;
        *(float4*)&bias_pre[j + 4] = oc;
        return;
    }
    const int wb = bid - 8192;
    const int qk = wb >> 4, h = wb & 15;
    const int e0 = threadIdx.x * 4;
    f32x4 acc[8];
    #pragma unroll
    for (int r = 0; r < 8; ++r) acc[r] = (f32x4){0.f, 0.f, 0.f, 0.f};
    #pragma unroll 4
    for (int d = 0; d < 64; ++d) {
        const float4 xv = *(const float4*)&Wqkv[(size_t)(qk * 1024 + h * 64 + d) * 1024 + e0];
        #pragma unroll
        for (int r = 0; r < 8; ++r) {
            const float w = W_recip[d * 8 + r];
            acc[r][0] = fmaf(w, xv.x, acc[r][0]);
            acc[r][1] = fmaf(w, xv.y, acc[r][1]);
            acc[r][2] = fmaf(w, xv.z, acc[r][2]);
            acc[r][3] = fmaf(w, xv.w, acc[r][3]);
        }
    }
    #pragma unroll
    for (int r = 0; r < 8; ++r) {
        ushort4 o;
        o.x = f2b(acc[r][0]); o.y = f2b(acc[r][1]);
        o.z = f2b(acc[r][2]); o.w = f2b(acc[r][3]);
        *(ushort4*)&wqkvb[(size_t)(3072 + qk * 128 + h * 8 + r) * 1024 + e0] = o;
    }
}

// ---------------------------------------------------------------------------
// bf16 MFMA GEMM core (128x128 tile, BK=64, 4 waves, global_load_lds staging,
// XOR-swizzled LDS: slot ^= row&7 on both the staging source and the
// fragment reads -> ds_read_b128 at minimal 2-way bank aliasing).
// ---------------------------------------------------------------------------
#define GEMM_CORE(Aptr, Bptr, KDIM, SMEMN)                                     \
    __shared__ __align__(16) ushort SMEM[SMEMN];                               \
    ushort* const Asl = SMEM;                                                  \
    ushort* const Bsl = SMEM + 8192;                                           \
    const int row0 = blockIdx.x * 128;                                         \
    const int col0 = blockIdx.y * 128;                                         \
    const int tid = threadIdx.x;                                               \
    const int wave = tid >> 6, lane = tid & 63;                                \
    const int wm = wave >> 1, wn = wave & 1;                                   \
    const int quad = lane >> 4, lq = lane & 15;                                \
    const int l7 = lq & 7;                                                     \
    f32x4 acc[4][4];                                                           \
    _Pragma("unroll") for (int i = 0; i < 4; ++i)                              \
        _Pragma("unroll") for (int j = 0; j < 4; ++j)                          \
            acc[i][j] = (f32x4){0.f, 0.f, 0.f, 0.f};                           \
    for (int k0 = 0; k0 < (KDIM); k0 += 64) {                                  \
        _Pragma("unroll") for (int p = 0; p < 4; ++p) {                        \
            const int idx = p * 256 + tid;                                     \
            const int row = idx >> 3, slot = idx & 7;                          \
            const int kc = (slot ^ (row & 7)) << 3;                            \
            gl2lds16(&(Aptr)[(size_t)(row0 + row) * (KDIM) + k0 + kc], &Asl[idx * 8]); \
            gl2lds16(&(Bptr)[(size_t)(col0 + row) * (KDIM) + k0 + kc], &Bsl[idx * 8]); \
        }                                                                      \
        __syncthreads();                                                       \
        _Pragma("unroll") for (int ks = 0; ks < 2; ++ks) {                     \
            short8 af[4], bf[4];                                               \
            _Pragma("unroll") for (int i = 0; i < 4; ++i)                      \
                af[i] = *(const short8*)&Asl[(wm * 64 + i * 16 + lq) * 64 +    \
                                             (((ks * 4 + quad) ^ l7) << 3)];   \
            _Pragma("unroll") for (int j = 0; j < 4; ++j)                      \
                bf[j] = *(const short8*)&Bsl[(wn * 64 + j * 16 + lq) * 64 +    \
                                             (((ks * 4 + quad) ^ l7) << 3)];   \
            _Pragma("unroll") for (int i = 0; i < 4; ++i)                      \
                _Pragma("unroll") for (int j = 0; j < 4; ++j)                  \
                    acc[i][j] = __builtin_amdgcn_mfma_f32_16x16x32_bf16(       \
                        af[i], bf[j], acc[i][j], 0, 0, 0);                     \
        }                                                                      \
        __syncthreads();                                                       \
    }

// Kernel 1: extended qkv GEMM, N=3328. 0.125*log2e attention scale folded
// into the q side (both main and k_low tail) so attn uses raw exp2.
__global__ __launch_bounds__(256, 4) void gemm_qkv_kernel(
    const ushort* __restrict__ A, const ushort* __restrict__ Bt,
    const float* __restrict__ w_std, const float* __restrict__ w_rec,
    ushort* __restrict__ qh, ushort* __restrict__ kh, ushort* __restrict__ vt)
{
    GEMM_CORE(A, Bt, 1024, 128 * 136)
    ushort* const Cs = SMEM;   // epilogue staging, overlays Asl/Bsl (safe)

    if (col0 >= 2048 && col0 < 3072) {
        // V region: vt[b][h][d][t], 4 consecutive t -> packed ushort4 store
        #pragma unroll
        for (int j = 0; j < 4; ++j) {
            const int cc = col0 + wn * 64 + j * 16 + lq;
            const int h = (cc >> 6) & 15;
            const int d = cc & 63;
            #pragma unroll
            for (int i = 0; i < 4; ++i) {
                const int rr0 = row0 + wm * 64 + i * 16 + quad * 4;
                const int b = rr0 >> 11, t0 = rr0 & 2047;
                ushort4 pv;
                pv.x = f2b(acc[i][j][0]); pv.y = f2b(acc[i][j][1]);
                pv.z = f2b(acc[i][j][2]); pv.w = f2b(acc[i][j][3]);
                *(ushort4*)&vt[((((size_t)b * NH + h) * HD + d) * T_SEQ + t0)] = pv;
            }
        }
    } else if (col0 < 2048) {
        // Q/K main: q scaled by w_std*0.125*log2e, k unscaled; d=0..55 only
        const bool isq = (col0 < 1024);
        #pragma unroll
        for (int j = 0; j < 4; ++j) {
            const int colc = wn * 64 + j * 16 + lq;
            const int h = ((col0 + colc) >> 6) & 15;
            const float sc = isq ? w_std[h] * (0.125f * LOG2E) : 1.0f;
            #pragma unroll
            for (int i = 0; i < 4; ++i)
                #pragma unroll
                for (int r = 0; r < 4; ++r)
                    Cs[(wm * 64 + i * 16 + quad * 4 + r) * 136 + colc] =
                        f2b(acc[i][j][r] * sc);
        }
        __syncthreads();
        ushort* dst = isq ? qh : kh;
        const int hbase = (col0 >> 6) & 15;
        #pragma unroll
        for (int rep = 0; rep < 8; ++rep) {
            const int id = rep * 256 + tid;
            const int row = id >> 4, chunk = id & 15;
            if ((chunk & 7) == 7) continue;   // d=56..63 owned by tail blocks
            const int h = hbase + (chunk >> 3);
            const int d = (chunk & 7) * 8;
            const int rr = row0 + row;
            const int b = rr >> 11, t = rr & 2047;
            const uint4 val = *(const uint4*)&Cs[row * 136 + chunk * 8];
            *(uint4*)&dst[((((size_t)b * NH + h) * T_SEQ + t) * HD + d)] = val;
        }
    } else {
        // Tail: q_low -> kh tails (unscaled); k_low -> qh tails (w_rec*0.125*log2e)
        const bool isqlow = (col0 < 3200);
        #pragma unroll
        for (int j = 0; j < 4; ++j) {
            const int colc = wn * 64 + j * 16 + lq;
            const int h = colc >> 3;
            const float sc = isqlow ? 1.0f : w_rec[h] * (0.125f * LOG2E);
            #pragma unroll
            for (int i = 0; i < 4; ++i)
                #pragma unroll
                for (int r = 0; r < 4; ++r)
                    Cs[(wm * 64 + i * 16 + quad * 4 + r) * 136 + colc] =
                        f2b(acc[i][j][r] * sc);
        }
        __syncthreads();
        ushort* dst = isqlow ? kh : qh;
        #pragma unroll
        for (int rep = 0; rep < 8; ++rep) {
            const int id = rep * 256 + tid;
            const int row = id >> 4, h = id & 15;
            const int rr = row0 + row;
            const int b = rr >> 11, t = rr & 2047;
            const uint4 val = *(const uint4*)&Cs[row * 136 + h * 8];
            *(uint4*)&dst[((((size_t)b * NH + h) * T_SEQ + t) * HD + 56)] = val;
        }
    }
}

// Kernel 4: out(f32) = ao @ Wproj^T.
__global__ __launch_bounds__(256, 4) void gemm_proj_kernel(
    const ushort* __restrict__ A, const ushort* __restrict__ Bt,
    float* __restrict__ C)
{
    GEMM_CORE(A, Bt, 1024, 16384)
    #pragma unroll
    for (int i = 0; i < 4; ++i) {
        #pragma unroll
        for (int r = 0; r < 4; ++r) {
            const int rr = row0 + wm * 64 + i * 16 + quad * 4 + r;
            #pragma unroll
            for (int j = 0; j < 4; ++j) {
                const int cc = col0 + wn * 64 + j * 16 + lq;
                C[(size_t)rr * 1024 + cc] = acc[i][j][r];
            }
        }
    }
}

// ---------------------------------------------------------------------------
// Kernel 3: MFMA attention, transposed formulation, PAIRED causal q-tiles.
// Block handles q-tiles qtA=y (light) and qtB=31-y (heavy): uniform 17
// chunk-computations per block, and each staged K/V chunk feeds 128 q-rows.
// P has a dedicated buffer -> no post-S barrier (1 barrier pair per chunk).
// Mask is always applied (no-op on interior chunks); on a tile's last chunk
// with even qt the upper 64 keys are fully masked -> NTL=4 skips them.
// ---------------------------------------------------------------------------
#define TILE_COMPUTE(bq, o4, lsum, qrow, NTL) do {                            \
    f32x4 s4[8];                                                              \
    _Pragma("unroll") for (int nt = 0; nt < (NTL); ++nt)                      \
        s4[nt] = *(const f32x4*)&bias_h[k0 + nt * 16 + quad * 4];             \
    _Pragma("unroll") for (int ks = 0; ks < 2; ++ks)                          \
        _Pragma("unroll") for (int nt = 0; nt < (NTL); ++nt) {                \
            const short8 ak = *(const short8*)                                \
                &Ks[(nt * 16 + lq) * 64 + (((ks * 4 + quad) ^ l7) << 3)];     \
            s4[nt] = __builtin_amdgcn_mfma_f32_16x16x32_bf16(                 \
                ak, (bq)[ks], s4[nt], 0, 0, 0);                               \
        }                                                                     \
    _Pragma("unroll") for (int nt = 0; nt < (NTL); ++nt) {                    \
        f32x4 sv = s4[nt];                                                    \
        const int kb = k0 + nt * 16 + quad * 4;                               \
        _Pragma("unroll") for (int r = 0; r < 4; ++r)                         \
            if (kb + r > (qrow)) sv[r] = NEGINF;                              \
        const float p0 = EXP2(sv[0]), p1 = EXP2(sv[1]);                       \
        const float p2 = EXP2(sv[2]), p3 = EXP2(sv[3]);                       \
        (lsum) += (p0 + p1) + (p2 + p3);                                      \
        const int pcol = (nt * 16 + quad * 4) ^ (l7 << 3);                    \
        uint2 pv; pv.x = pack_bf16(p0, p1); pv.y = pack_bf16(p2, p3);         \
        *(uint2*)&Ps[prow + pcol] = pv;                                       \
    }                                                                         \
    _Pragma("unroll") for (int ks = 0; ks < (NTL) / 2; ++ks) {                \
        const short8 bp = *(const short8*)                                    \
            &Ps[prow + ((ks * 32 + quad * 8) ^ (l7 << 3))];                   \
        _Pragma("unroll") for (int dt = 0; dt < 4; ++dt) {                    \
            const short8 av = *(const short8*)                                \
                &Vs[(dt * 16 + lq) * 128 + (((ks * 4 + quad) ^ lq) << 3)];    \
            (o4)[dt] = __builtin_amdgcn_mfma_f32_16x16x32_bf16(               \
                av, bp, (o4)[dt], 0, 0, 0);                                   \
        }                                                                     \
    }                                                                         \
} while (0)

__global__ __launch_bounds__(256, 2) void attn_kernel(
    const ushort* __restrict__ qa, const ushort* __restrict__ ka,
    const ushort* __restrict__ vt, const float* __restrict__ bias_pre,
    ushort* __restrict__ out)
{
    __shared__ __align__(16) ushort Qs[2 * 64 * 64];   // 16 KiB (tiles A,B)
    __shared__ __align__(16) ushort Ks[128 * 64];      // 16 KiB
    __shared__ __align__(16) ushort Ps[64 * 128];      // 16 KiB (dedicated P)
    __shared__ __align__(16) ushort Vs[64 * 128];      // 16 KiB
    const int bh = blockIdx.x;
    const int qtA = blockIdx.y;        // light tile (0..15)
    const int qtB = 31 - blockIdx.y;   // heavy tile (16..31)
    const int h = bh & 15, b = bh >> 4;
    const int tid = threadIdx.x;
    const int wave = tid >> 6, lane = tid & 63;
    const int quad = lane >> 4, lq = lane & 15;
    const int l7 = lq & 7;
    const size_t base = (size_t)bh * T_SEQ * HD;

    // Q stage for both tiles (once), swizzled source -> linear LDS
    #pragma unroll
    for (int rep = 0; rep < 2; ++rep) {
        const int idx = rep * 256 + tid;
        const int row = idx >> 3, slot = idx & 7;
        const int kc = (slot ^ (row & 7)) << 3;
        gl2lds16(&qa[base + (size_t)(qtA * 64 + row) * 64 + kc], &Qs[idx * 8]);
        gl2lds16(&qa[base + (size_t)(qtB * 64 + row) * 64 + kc], &Qs[4096 + idx * 8]);
    }
    __syncthreads();
    short8 bqA[2], bqB[2];
    #pragma unroll
    for (int ks = 0; ks < 2; ++ks) {
        const int off = (wave * 16 + lq) * 64 + (((ks * 4 + quad) ^ l7) << 3);
        bqA[ks] = *(const short8*)&Qs[off];
        bqB[ks] = *(const short8*)&Qs[4096 + off];
    }

    f32x4 o4A[4], o4B[4];
    #pragma unroll
    for (int dt = 0; dt < 4; ++dt) {
        o4A[dt] = (f32x4){0.f, 0.f, 0.f, 0.f};
        o4B[dt] = (f32x4){0.f, 0.f, 0.f, 0.f};
    }
    float lsumA = 0.f, lsumB = 0.f;
    const int qrowA = qtA * 64 + wave * 16 + lq;
    const int qrowB = qtB * 64 + wave * 16 + lq;
    const int prow = (wave * 16 + lq) * 128;
    const int nA = (qtA + 2) >> 1, nB = (qtB + 2) >> 1;
    const float* bias_h = &bias_pre[h * T_SEQ];

    for (int c = 0; c < nB; ++c) {
        const int k0 = c * 128;
        if (c) __syncthreads();   // prev chunk's K/V reads done before restage
        #pragma unroll
        for (int rep = 0; rep < 4; ++rep) {
            const int idx = rep * 256 + tid;
            const int row = idx >> 3, slot = idx & 7;
            gl2lds16(&ka[base + (size_t)(k0 + row) * 64 + ((slot ^ (row & 7)) << 3)],
                     &Ks[idx * 8]);
        }
        #pragma unroll
        for (int rep = 0; rep < 4; ++rep) {
            const int idx = rep * 256 + tid;
            const int row = idx >> 4, slot = idx & 15;
            gl2lds16(&vt[base + (size_t)row * T_SEQ + k0 + ((slot ^ (row & 15)) << 3)],
                     &Vs[idx * 8]);
        }
        __syncthreads();

        // heavy tile (always active)
        if (c == nB - 1 && !(qtB & 1)) TILE_COMPUTE(bqB, o4B, lsumB, qrowB, 4);
        else                           TILE_COMPUTE(bqB, o4B, lsumB, qrowB, 8);
        // light tile
        if (c < nA) {
            if (c == nA - 1 && !(qtA & 1)) TILE_COMPUTE(bqA, o4A, lsumA, qrowA, 4);
            else                           TILE_COMPUTE(bqA, o4A, lsumA, qrowA, 8);
        }
    }

    // row sums: lanes {lq, lq+16, lq+32, lq+48} hold disjoint key subsets
    lsumA += __shfl_xor(lsumA, 16, 64);
    lsumA += __shfl_xor(lsumA, 32, 64);
    lsumB += __shfl_xor(lsumB, 16, 64);
    lsumB += __shfl_xor(lsumB, 32, 64);
    const float invA = 1.0f / lsumA, invB = 1.0f / lsumB;
    const size_t obaseA = ((size_t)b * T_SEQ + qrowA) * CEMB + h * HD;
    const size_t obaseB = ((size_t)b * T_SEQ + qrowB) * CEMB + h * HD;
    #pragma unroll
    for (int dt = 0; dt < 4; ++dt) {
        ushort4 ov;
        ov.x = f2b_fast(o4A[dt][0] * invA);
        ov.y = f2b_fast(o4A[dt][1] * invA);
        ov.z = f2b_fast(o4A[dt][2] * invA);
        ov.w = f2b_fast(o4A[dt][3] * invA);
        *(ushort4*)&out[obaseA + dt * 16 + quad * 4] = ov;
        ushort4 ow;
        ow.x = f2b_fast(o4B[dt][0] * invB);
        ow.y = f2b_fast(o4B[dt][1] * invB);
        ow.z = f2b_fast(o4B[dt][2] * invB);
        ow.w = f2b_fast(o4B[dt][3] * invB);
        *(ushort4*)&out[obaseB + dt * 16 + quad * 4] = ow;
    }
}

// ---------------------------------------------------------------------------
extern "C" void kernel_launch(void* const* d_in, const int* in_sizes, int n_in,
                              void* d_out, int out_size, void* d_ws, size_t ws_size,
                              hipStream_t stream) {
    const float* x       = (const float*)d_in[0];
    const float* Wqkv    = (const float*)d_in[1];
    const float* Wproj   = (const float*)d_in[2];
    const float* W_recip = (const float*)d_in[3];
    const float* w_std   = (const float*)d_in[4];
    const float* w_rec   = (const float*)d_in[5];
    const float* w_disc  = (const float*)d_in[6];
    const float* d_bias  = (const float*)d_in[7];
    float* out = (float*)d_out;

    const size_t NX = (size_t)4096 * 1024;
    const size_t NWQKVX = (size_t)3328 * 1024;
    const size_t NWPROJ = (size_t)1024 * 1024;
    ushort* xb     = (ushort*)d_ws;
    ushort* wqkvb  = xb + NX;
    ushort* wprojb = wqkvb + NWQKVX;
    ushort* qh     = wprojb + NWPROJ;
    ushort* kh     = qh + NX;
    ushort* vt     = kh + NX;
    ushort* ao     = vt + NX;
    float*  bias_pre = (float*)(ao + NX);   // 16*2048 f32 = 128 KiB

    prep_kernel<<<8240, 256, 0, stream>>>(x, Wqkv, Wproj, W_recip, w_disc, d_bias,
                                          xb, wqkvb, wprojb, bias_pre);
    gemm_qkv_kernel<<<dim3(32, 26), 256, 0, stream>>>(xb, wqkvb, w_std, w_rec, qh, kh, vt);
    attn_kernel<<<dim3(32, 16), 256, 0, stream>>>(qh, kh, vt, bias_pre, ao);
    gemm_proj_kernel<<<dim3(32, 8), 256, 0, stream>>>(ao, wprojb, out);
}